// Round 3
// baseline (229.882 us; speedup 1.0000x reference)
//
#include <hip/hip_runtime.h>
#include <math.h>

#define D_INNER 5120
#define DT_RANK 160
#define N_STATE 16
#define BATCH   256
#define KTOT    192               // 160 (dt_low) | 16 (B) | 16 (C)

// ---- K1 config: 256-thr blocks, 4 waves x 40-dd chunks, intra-block reduce ----
#define BGRP    8                 // batches per block
#define NBG     (BATCH / BGRP)    // 32
#define DDBLK   160               // dd per block (4 waves x 40)
#define NDDB    (D_INNER / DDBLK) // 32 -> SPLIT partials
#define SPLIT   32

// ---- K3a config: delta GEMM, 4 batches/block, grid (20,64)=1280 blocks ----
#define K3A_BT  4
// ---- K3b config: scan, 2 batches/thread, grid (20,128)=2560 blocks ----
#define K3B_BT  2

// ---- workspace layout (float offsets) ----
#define OFF_T     0
#define SZ_T      (BATCH * KTOT)                  // 49,152
#define OFF_P     (OFF_T + SZ_T)
#define SZ_P      (SPLIT * BATCH * KTOT)          // 1,572,864 (6.3 MB)
#define OFF_SBC   (OFF_P + SZ_P)                  // sbc[b]
#define OFF_DELTA (OFF_SBC + BATCH)               // delta[B][D] (5.2 MB)

// ---------------------------------------------------------------------------
// K1: projection GEMM partials (unchanged, ~10 us).
// ---------------------------------------------------------------------------
__global__ __launch_bounds__(256) void k1_gemm(const float* __restrict__ x,
                                               const float* __restrict__ Wdtlow,
                                               const float* __restrict__ WB,
                                               const float* __restrict__ WC,
                                               float* __restrict__ ws) {
    __shared__ float lds[4 * BGRP * KTOT];   // 6144 floats = 24 KB
    const int tid  = threadIdx.x;
    const int lane = tid & 63;
    const int wv   = tid >> 6;               // wave 0..3
    const int b0   = blockIdx.x * BGRP;
    const int ddB  = blockIdx.y * DDBLK;

    float* xs = lds;
    for (int j = tid; j < (BGRP * DDBLK) / 4; j += 256) {   // 320 float4
        int i  = j / (DDBLK / 4);
        int c4 = j % (DDBLK / 4);
        float4 v = *(const float4*)(x + (size_t)(b0 + i) * D_INNER + ddB + c4 * 4);
        *(float4*)(xs + i * DDBLK + c4 * 4) = v;
    }
    __syncthreads();

    const int dd0 = wv * 40;
    const float* p0 = Wdtlow + (size_t)(ddB + dd0) * DT_RANK + lane;
    const float* p1 = p0 + 64;
    const float* p2;
    int st2;
    if (lane < 32)      { p2 = p0 + 128;                                          st2 = DT_RANK; }
    else if (lane < 48) { p2 = WB + (size_t)(ddB + dd0) * N_STATE + (lane - 32);  st2 = N_STATE; }
    else                { p2 = WC + (size_t)(ddB + dd0) * N_STATE + (lane - 48);  st2 = N_STATE; }

    float acc0[BGRP], acc1[BGRP], acc2[BGRP];
#pragma unroll
    for (int i = 0; i < BGRP; ++i) { acc0[i] = 0.f; acc1[i] = 0.f; acc2[i] = 0.f; }

#pragma unroll 2
    for (int g = 0; g < 10; ++g) {           // 4 dd per group
        float w0[4], w1[4], w2[4];
#pragma unroll
        for (int u = 0; u < 4; ++u) {
            int dd = g * 4 + u;
            w0[u] = p0[(size_t)dd * DT_RANK];
            w1[u] = p1[(size_t)dd * DT_RANK];
            w2[u] = p2[(size_t)dd * st2];
        }
#pragma unroll
        for (int i = 0; i < BGRP; ++i) {
            float4 xv = *(const float4*)(xs + i * DDBLK + dd0 + g * 4);
            acc0[i] += xv.x * w0[0] + xv.y * w0[1] + xv.z * w0[2] + xv.w * w0[3];
            acc1[i] += xv.x * w1[0] + xv.y * w1[1] + xv.z * w1[2] + xv.w * w1[3];
            acc2[i] += xv.x * w2[0] + xv.y * w2[1] + xv.z * w2[2] + xv.w * w2[3];
        }
    }
    __syncthreads();

#pragma unroll
    for (int i = 0; i < BGRP; ++i) {
        float* r = lds + wv * (BGRP * KTOT) + i * KTOT;
        r[lane]       = acc0[i];
        r[lane + 64]  = acc1[i];
        r[lane + 128] = acc2[i];
    }
    __syncthreads();

    float* P = ws + OFF_P + (size_t)blockIdx.y * (BATCH * KTOT) + (size_t)b0 * KTOT;
#pragma unroll
    for (int r = 0; r < 6; ++r) {
        int idx = tid + r * 256;
        P[idx] = lds[idx] + lds[idx + 1536] + lds[idx + 3072] + lds[idx + 4608];
    }
}

// ---------------------------------------------------------------------------
// K2: reduce split-K partials -> T[256][192], plus hoisted sbc[b].
// (unchanged)
// ---------------------------------------------------------------------------
__global__ __launch_bounds__(192) void k2_reduce(float* __restrict__ ws) {
    __shared__ float ts[KTOT];
    const int b   = blockIdx.x;
    const int col = threadIdx.x;
    const float* P = ws + OFF_P + (size_t)b * KTOT + col;
    float a = 0.f;
#pragma unroll
    for (int s = 0; s < SPLIT; ++s) a += P[(size_t)s * (BATCH * KTOT)];
    ws[OFF_T + b * KTOT + col] = a;
    ts[col] = a;
    __syncthreads();
    if (col == 0) {
        float s2 = 0.f;
#pragma unroll
        for (int n = 0; n < N_STATE; ++n) s2 += ts[160 + n] * ts[176 + n];
        ws[OFF_SBC + b] = s2;
    }
}

// ---------------------------------------------------------------------------
// K3a: delta pre-activation GEMM + softplus -> ws[OFF_DELTA].
// Round-3: unroll 16 (16 Wdt loads in flight per wave; ~45 VGPR fits the
// 64-VGPR cap from __launch_bounds__(256,8)). Grid (20,64)=1280 blocks.
// ---------------------------------------------------------------------------
__global__ __launch_bounds__(256, 8) void k3a_delta(const float* __restrict__ Wdt,
                                                    const float* __restrict__ b_dt,
                                                    float* __restrict__ ws) {
    const int tid = threadIdx.x;
    const int d   = blockIdx.x * 256 + tid;
    const int b0  = blockIdx.y * K3A_BT;
    const float* T = ws + OFF_T;

    // T rows wave-uniform -> scalar loads; Wdt k-major coalesced.
    float acc[K3A_BT] = {0.f, 0.f, 0.f, 0.f};
#pragma unroll 16
    for (int k = 0; k < DT_RANK; ++k) {
        float w = Wdt[(size_t)k * D_INNER + d];
#pragma unroll
        for (int i = 0; i < K3A_BT; ++i)
            acc[i] += T[(size_t)(b0 + i) * KTOT + k] * w;
    }

    const float bdt = b_dt[d];
#pragma unroll
    for (int i = 0; i < K3A_BT; ++i) {
        float v     = acc[i] + bdt;
        float delta = (v > 20.f) ? v : log1pf(__expf(v));
        ws[OFF_DELTA + (size_t)(b0 + i) * D_INNER + d] = delta;   // coalesced
    }
}

// ---------------------------------------------------------------------------
// K3b: pure streaming scan, 2 batches per thread.
// Round-3 fix: __launch_bounds__(256,8) had capped VGPR at 64 while the body
// needs ~55-60 -> near-certain scratch spills in the hot path (the suspected
// cause of the split's null result). Now (256,4): cap 128, ~90 VGPR used,
// zero spill; 16 waves/CU x 8KB h0 in flight = 128 KB/CU >> 22 KB/CU needed
// for 6.3 TB/s (Little's law). A[d] loaded once, reused for both batches
// (halves A's 84MB of cache read traffic). Grid (20,128)=2560 blocks.
// ---------------------------------------------------------------------------
__global__ __launch_bounds__(256, 4) void k3b_scan(const float* __restrict__ x,
                                                   const float* __restrict__ A,
                                                   const float* __restrict__ Dv,
                                                   const float* __restrict__ h0,
                                                   const float* __restrict__ ws,
                                                   float* __restrict__ out) {
    const int tid = threadIdx.x;
    const int d   = blockIdx.x * 256 + tid;
    const int b0  = blockIdx.y * K3B_BT;

    // issue ALL long-latency loads first: h0 for both batches (8 dwordx4)
    const float4* hpA = (const float4*)(h0 + ((size_t)b0 * D_INNER + d) * N_STATE);
    const float4* hpB = (const float4*)(h0 + ((size_t)(b0 + 1) * D_INNER + d) * N_STATE);
    float4 hA0 = hpA[0], hA1 = hpA[1], hA2 = hpA[2], hA3 = hpA[3];
    float4 hB0 = hpB[0], hB1 = hpB[1], hB2 = hpB[2], hB3 = hpB[3];

    const float4* a4 = (const float4*)(A + (size_t)d * N_STATE);
    float4 a0 = a4[0], a1 = a4[1], a2 = a4[2], a3 = a4[3];

    const size_t bdA = (size_t)b0 * D_INNER + d;
    const size_t bdB = bdA + D_INNER;
    float dltA = ws[OFF_DELTA + bdA];
    float dltB = ws[OFF_DELTA + bdB];
    float xvA  = x[bdA];
    float xvB  = x[bdB];
    const float Dd = Dv[d];

    const float* TbA = ws + OFF_T + (size_t)b0 * KTOT;       // uniform -> s_loads
    const float* TbB = TbA + KTOT;
    float sbcA = ws[OFF_SBC + b0];
    float sbcB = ws[OFF_SBC + b0 + 1];

    // batch A: 4 partials (short exp chains)
    float y0, y1, y2, y3;
    y0  = __expf(dltA * a0.x) * hA0.x * TbA[176 + 0];
    y0 += __expf(dltA * a0.y) * hA0.y * TbA[176 + 1];
    y0 += __expf(dltA * a0.z) * hA0.z * TbA[176 + 2];
    y0 += __expf(dltA * a0.w) * hA0.w * TbA[176 + 3];
    y1  = __expf(dltA * a1.x) * hA1.x * TbA[176 + 4];
    y1 += __expf(dltA * a1.y) * hA1.y * TbA[176 + 5];
    y1 += __expf(dltA * a1.z) * hA1.z * TbA[176 + 6];
    y1 += __expf(dltA * a1.w) * hA1.w * TbA[176 + 7];
    y2  = __expf(dltA * a2.x) * hA2.x * TbA[176 + 8];
    y2 += __expf(dltA * a2.y) * hA2.y * TbA[176 + 9];
    y2 += __expf(dltA * a2.z) * hA2.z * TbA[176 + 10];
    y2 += __expf(dltA * a2.w) * hA2.w * TbA[176 + 11];
    y3  = __expf(dltA * a3.x) * hA3.x * TbA[176 + 12];
    y3 += __expf(dltA * a3.y) * hA3.y * TbA[176 + 13];
    y3 += __expf(dltA * a3.z) * hA3.z * TbA[176 + 14];
    y3 += __expf(dltA * a3.w) * hA3.w * TbA[176 + 15];
    out[bdA] = xvA * (Dd + dltA * sbcA) + ((y0 + y1) + (y2 + y3));

    // batch B: reuses a0..a3 and Dd
    y0  = __expf(dltB * a0.x) * hB0.x * TbB[176 + 0];
    y0 += __expf(dltB * a0.y) * hB0.y * TbB[176 + 1];
    y0 += __expf(dltB * a0.z) * hB0.z * TbB[176 + 2];
    y0 += __expf(dltB * a0.w) * hB0.w * TbB[176 + 3];
    y1  = __expf(dltB * a1.x) * hB1.x * TbB[176 + 4];
    y1 += __expf(dltB * a1.y) * hB1.y * TbB[176 + 5];
    y1 += __expf(dltB * a1.z) * hB1.z * TbB[176 + 6];
    y1 += __expf(dltB * a1.w) * hB1.w * TbB[176 + 7];
    y2  = __expf(dltB * a2.x) * hB2.x * TbB[176 + 8];
    y2 += __expf(dltB * a2.y) * hB2.y * TbB[176 + 9];
    y2 += __expf(dltB * a2.z) * hB2.z * TbB[176 + 10];
    y2 += __expf(dltB * a2.w) * hB2.w * TbB[176 + 11];
    y3  = __expf(dltB * a3.x) * hB3.x * TbB[176 + 12];
    y3 += __expf(dltB * a3.y) * hB3.y * TbB[176 + 13];
    y3 += __expf(dltB * a3.z) * hB3.z * TbB[176 + 14];
    y3 += __expf(dltB * a3.w) * hB3.w * TbB[176 + 15];
    out[bdB] = xvB * (Dd + dltB * sbcB) + ((y0 + y1) + (y2 + y3));
}

// ---------------------------------------------------------------------------
extern "C" void kernel_launch(void* const* d_in, const int* in_sizes, int n_in,
                              void* d_out, int out_size, void* d_ws, size_t ws_size,
                              hipStream_t stream) {
    const float* x      = (const float*)d_in[0];
    const float* Wdtlow = (const float*)d_in[1];
    const float* Wdt    = (const float*)d_in[2];
    const float* bdt    = (const float*)d_in[3];
    const float* WB     = (const float*)d_in[4];
    const float* WC     = (const float*)d_in[5];
    const float* A      = (const float*)d_in[6];
    const float* Dv     = (const float*)d_in[7];
    const float* h0     = (const float*)d_in[8];
    float* ws  = (float*)d_ws;
    float* out = (float*)d_out;

    // K1: projection GEMM partials (1024 blocks, unchanged)
    hipLaunchKernelGGL(k1_gemm, dim3(NBG, NDDB), dim3(256), 0, stream,
                       x, Wdtlow, WB, WC, ws);
    // K2: reduce partials -> T[256][192] + sbc[256]
    hipLaunchKernelGGL(k2_reduce, dim3(BATCH), dim3(192), 0, stream, ws);
    // K3a: delta GEMM + softplus (1280 blocks)
    hipLaunchKernelGGL(k3a_delta, dim3(D_INNER / 256, BATCH / K3A_BT), dim3(256),
                       0, stream, Wdt, bdt, ws);
    // K3b: pure streaming scan, 2 batches/thread (2560 blocks, no spills)
    hipLaunchKernelGGL(k3b_scan, dim3(D_INNER / 256, BATCH / K3B_BT), dim3(256),
                       0, stream, x, A, Dv, h0, ws, out);
}

// Round 4
// 173.086 us; speedup vs baseline: 1.3281x; 1.3281x over previous
//
#include <hip/hip_runtime.h>
#include <math.h>

#define D_INNER 5120
#define DT_RANK 160
#define N_STATE 16
#define BATCH   256
#define KTOT    192               // 160 (dt_low) | 16 (B) | 16 (C)

// ---- K1 config: 256-thr blocks, 4 waves x 40-dd chunks, intra-block reduce ----
#define BGRP    8                 // batches per block
#define NBG     (BATCH / BGRP)    // 32
#define DDBLK   160               // dd per block (4 waves x 40)
#define NDDB    (D_INNER / DDBLK) // 32 -> SPLIT partials
#define SPLIT   32

// ---- K3 config: FUSED (round-0 structure), 4 batches/block, grid (20,64) ----
#define K3_BT   4

// ---- workspace layout (float offsets) ----
#define OFF_T     0
#define SZ_T      (BATCH * KTOT)                  // 49,152
#define OFF_P     (OFF_T + SZ_T)
#define SZ_P      (SPLIT * BATCH * KTOT)          // 1,572,864 (6.3 MB)
#define OFF_SBC   (OFF_P + SZ_P)                  // sbc[b] = sum_n T[b][160+n]*T[b][176+n]

// ---------------------------------------------------------------------------
// K1: projection GEMM partials (unchanged, ~10 us).
// ---------------------------------------------------------------------------
__global__ __launch_bounds__(256) void k1_gemm(const float* __restrict__ x,
                                               const float* __restrict__ Wdtlow,
                                               const float* __restrict__ WB,
                                               const float* __restrict__ WC,
                                               float* __restrict__ ws) {
    __shared__ float lds[4 * BGRP * KTOT];   // 6144 floats = 24 KB
    const int tid  = threadIdx.x;
    const int lane = tid & 63;
    const int wv   = tid >> 6;               // wave 0..3
    const int b0   = blockIdx.x * BGRP;
    const int ddB  = blockIdx.y * DDBLK;

    float* xs = lds;
    for (int j = tid; j < (BGRP * DDBLK) / 4; j += 256) {   // 320 float4
        int i  = j / (DDBLK / 4);
        int c4 = j % (DDBLK / 4);
        float4 v = *(const float4*)(x + (size_t)(b0 + i) * D_INNER + ddB + c4 * 4);
        *(float4*)(xs + i * DDBLK + c4 * 4) = v;
    }
    __syncthreads();

    const int dd0 = wv * 40;
    const float* p0 = Wdtlow + (size_t)(ddB + dd0) * DT_RANK + lane;
    const float* p1 = p0 + 64;
    const float* p2;
    int st2;
    if (lane < 32)      { p2 = p0 + 128;                                          st2 = DT_RANK; }
    else if (lane < 48) { p2 = WB + (size_t)(ddB + dd0) * N_STATE + (lane - 32);  st2 = N_STATE; }
    else                { p2 = WC + (size_t)(ddB + dd0) * N_STATE + (lane - 48);  st2 = N_STATE; }

    float acc0[BGRP], acc1[BGRP], acc2[BGRP];
#pragma unroll
    for (int i = 0; i < BGRP; ++i) { acc0[i] = 0.f; acc1[i] = 0.f; acc2[i] = 0.f; }

#pragma unroll 2
    for (int g = 0; g < 10; ++g) {           // 4 dd per group
        float w0[4], w1[4], w2[4];
#pragma unroll
        for (int u = 0; u < 4; ++u) {
            int dd = g * 4 + u;
            w0[u] = p0[(size_t)dd * DT_RANK];
            w1[u] = p1[(size_t)dd * DT_RANK];
            w2[u] = p2[(size_t)dd * st2];
        }
#pragma unroll
        for (int i = 0; i < BGRP; ++i) {
            float4 xv = *(const float4*)(xs + i * DDBLK + dd0 + g * 4);
            acc0[i] += xv.x * w0[0] + xv.y * w0[1] + xv.z * w0[2] + xv.w * w0[3];
            acc1[i] += xv.x * w1[0] + xv.y * w1[1] + xv.z * w1[2] + xv.w * w1[3];
            acc2[i] += xv.x * w2[0] + xv.y * w2[1] + xv.z * w2[2] + xv.w * w2[3];
        }
    }
    __syncthreads();

#pragma unroll
    for (int i = 0; i < BGRP; ++i) {
        float* r = lds + wv * (BGRP * KTOT) + i * KTOT;
        r[lane]       = acc0[i];
        r[lane + 64]  = acc1[i];
        r[lane + 128] = acc2[i];
    }
    __syncthreads();

    float* P = ws + OFF_P + (size_t)blockIdx.y * (BATCH * KTOT) + (size_t)b0 * KTOT;
#pragma unroll
    for (int r = 0; r < 6; ++r) {
        int idx = tid + r * 256;
        P[idx] = lds[idx] + lds[idx + 1536] + lds[idx + 3072] + lds[idx + 4608];
    }
}

// ---------------------------------------------------------------------------
// K2: reduce split-K partials -> T[256][192], plus hoisted sbc[b].
// (unchanged; proven across rounds 1-3)
// ---------------------------------------------------------------------------
__global__ __launch_bounds__(192) void k2_reduce(float* __restrict__ ws) {
    __shared__ float ts[KTOT];
    const int b   = blockIdx.x;
    const int col = threadIdx.x;
    const float* P = ws + OFF_P + (size_t)b * KTOT + col;
    float a = 0.f;
#pragma unroll
    for (int s = 0; s < SPLIT; ++s) a += P[(size_t)s * (BATCH * KTOT)];
    ws[OFF_T + b * KTOT + col] = a;
    ts[col] = a;
    __syncthreads();
    if (col == 0) {
        float s2 = 0.f;
#pragma unroll
        for (int n = 0; n < N_STATE; ++n) s2 += ts[160 + n] * ts[176 + n];
        ws[OFF_SBC + b] = s2;
    }
}

// ---------------------------------------------------------------------------
// K3: FUSED delta GEMM + softplus + scan — round-0 structure (the measured
// best: ~44 us), with the one clean improvement learned since:
//   * h0 batches 0,1 and all 4 x values are ISSUED BEFORE the GEMM loop
//     (issue-early/consume-late): their ~900cy HBM latency hides under the
//     160-iteration Wdt GEMM phase, and the scan's 2-deep prefetch has all
//     4 h0 batches in flight by iteration 1.
//   * sbc[b] from K2 (1 s_load) instead of 16 FMA + 32 s_loads per (b,d).
//   * y in 4 partials (exp dependency chain 16 -> 4).
// What we do NOT repeat: BT=8 (round 1: grid 640 -> latency-bound, 51us),
// the k3a/k3b split (rounds 2-3: serializes L2-GEMM vs HBM-stream, 50-98us),
// unroll 16 under a tight VGPR cap (round 3: allocator collapsed to 12 VGPR).
// __launch_bounds__(256,5): cap 102 VGPR (need ~95 with the 2-batch h0
// prefetch live across the GEMM). Resident waves unchanged at 20/CU —
// grid-limited (1280 blocks = 5 blocks/CU x 4 waves), so the relaxed cap
// costs zero occupancy vs round-0's (256,6).
// ---------------------------------------------------------------------------
__global__ __launch_bounds__(256, 5) void k3_fused(const float* __restrict__ Wdt,
                                                   const float* __restrict__ b_dt,
                                                   const float* __restrict__ x,
                                                   const float* __restrict__ A,
                                                   const float* __restrict__ Dv,
                                                   const float* __restrict__ h0,
                                                   const float* __restrict__ ws,
                                                   float* __restrict__ out) {
    const int tid = threadIdx.x;
    const int d   = blockIdx.x * 256 + tid;
    const int b0  = blockIdx.y * K3_BT;
    const float* T  = ws + OFF_T;
    const float* SB = ws + OFF_SBC;

    // ---- issue long-latency HBM loads FIRST: h0 batches 0,1 + x[0..3] ----
    const float4* hb = (const float4*)(h0 + ((size_t)b0 * D_INNER + d) * N_STATE);
    const size_t  hstride = (size_t)D_INNER * 4;     // float4s per batch step

    float4 hc0 = hb[0], hc1 = hb[1], hc2 = hb[2], hc3 = hb[3];
    const float4* h1p = hb + hstride;
    float4 hn0 = h1p[0], hn1 = h1p[1], hn2 = h1p[2], hn3 = h1p[3];

    float xv[K3_BT];
#pragma unroll
    for (int i = 0; i < K3_BT; ++i) xv[i] = x[(size_t)(b0 + i) * D_INNER + d];

    const float bdt = b_dt[d];
    const float Dd  = Dv[d];
    const float4* a4 = (const float4*)(A + (size_t)d * N_STATE);
    float4 a0 = a4[0], a1 = a4[1], a2 = a4[2], a3 = a4[3];

    // ---- delta pre-activation GEMM: acc[i] = T[b0+i][0..159] . Wdt[:,d] ----
    // T rows wave-uniform -> s_loads; Wdt k-major coalesced (1KB/wave/k).
    // unroll 8 (round-0 proven codegen; do NOT raise under a VGPR cap).
    float acc[K3_BT] = {0.f, 0.f, 0.f, 0.f};
#pragma unroll 8
    for (int k = 0; k < DT_RANK; ++k) {
        float w = Wdt[(size_t)k * D_INNER + d];
#pragma unroll
        for (int i = 0; i < K3_BT; ++i)
            acc[i] += T[(size_t)(b0 + i) * KTOT + k] * w;
    }

    // ---- scan over 4 batches, 2-deep h0 prefetch (batches 2,3 issue
    // during iterations 0,1 while their compute is still >1 iter away) ----
#pragma unroll
    for (int i = 0; i < K3_BT; ++i) {
        float4 p0, p1, p2, p3;
        if (i + 2 < K3_BT) {                          // prefetch batch i+2
            const float4* hp = hb + (size_t)(i + 2) * hstride;
            p0 = hp[0]; p1 = hp[1]; p2 = hp[2]; p3 = hp[3];
        }

        const int b = b0 + i;
        const float* Tb = T + (size_t)b * KTOT;       // uniform -> s_loads

        float v     = acc[i] + bdt;
        float delta = (v > 20.f) ? v : log1pf(__expf(v));
        float sbc   = SB[b];                          // hoisted to K2

        float y0, y1, y2, y3;                         // 4 partials: short chains
        y0  = __expf(delta * a0.x) * hc0.x * Tb[176 + 0];
        y0 += __expf(delta * a0.y) * hc0.y * Tb[176 + 1];
        y0 += __expf(delta * a0.z) * hc0.z * Tb[176 + 2];
        y0 += __expf(delta * a0.w) * hc0.w * Tb[176 + 3];
        y1  = __expf(delta * a1.x) * hc1.x * Tb[176 + 4];
        y1 += __expf(delta * a1.y) * hc1.y * Tb[176 + 5];
        y1 += __expf(delta * a1.z) * hc1.z * Tb[176 + 6];
        y1 += __expf(delta * a1.w) * hc1.w * Tb[176 + 7];
        y2  = __expf(delta * a2.x) * hc2.x * Tb[176 + 8];
        y2 += __expf(delta * a2.y) * hc2.y * Tb[176 + 9];
        y2 += __expf(delta * a2.z) * hc2.z * Tb[176 + 10];
        y2 += __expf(delta * a2.w) * hc2.w * Tb[176 + 11];
        y3  = __expf(delta * a3.x) * hc3.x * Tb[176 + 12];
        y3 += __expf(delta * a3.y) * hc3.y * Tb[176 + 13];
        y3 += __expf(delta * a3.z) * hc3.z * Tb[176 + 14];
        y3 += __expf(delta * a3.w) * hc3.w * Tb[176 + 15];

        out[(size_t)b * D_INNER + d] = xv[i] * (Dd + delta * sbc)
                                     + ((y0 + y1) + (y2 + y3));

        if (i < K3_BT - 1) { hc0 = hn0; hc1 = hn1; hc2 = hn2; hc3 = hn3; }
        if (i + 2 < K3_BT) { hn0 = p0;  hn1 = p1;  hn2 = p2;  hn3 = p3;  }
    }
}

// ---------------------------------------------------------------------------
extern "C" void kernel_launch(void* const* d_in, const int* in_sizes, int n_in,
                              void* d_out, int out_size, void* d_ws, size_t ws_size,
                              hipStream_t stream) {
    const float* x      = (const float*)d_in[0];
    const float* Wdtlow = (const float*)d_in[1];
    const float* Wdt    = (const float*)d_in[2];
    const float* bdt    = (const float*)d_in[3];
    const float* WB     = (const float*)d_in[4];
    const float* WC     = (const float*)d_in[5];
    const float* A      = (const float*)d_in[6];
    const float* Dv     = (const float*)d_in[7];
    const float* h0     = (const float*)d_in[8];
    float* ws  = (float*)d_ws;
    float* out = (float*)d_out;

    // K1: projection GEMM partials (1024 blocks, unchanged)
    hipLaunchKernelGGL(k1_gemm, dim3(NBG, NDDB), dim3(256), 0, stream,
                       x, Wdtlow, WB, WC, ws);
    // K2: reduce partials -> T[256][192] + sbc[256]
    hipLaunchKernelGGL(k2_reduce, dim3(BATCH), dim3(192), 0, stream, ws);
    // K3: fused delta GEMM + scan, BT=4, grid (20,64)=1280 blocks
    hipLaunchKernelGGL(k3_fused, dim3(D_INNER / 256, BATCH / K3_BT), dim3(256),
                       0, stream, Wdt, bdt, x, A, Dv, h0, ws, out);
}